// Round 13
// baseline (372.909 us; speedup 1.0000x reference)
//
#include <hip/hip_runtime.h>
#include <math.h>

#define N_NODES 100000
#define N_EDGES 400000
#define NG 2048
#define H 128
#define NV 100
#define NLAYERS 3
#define SLOPE 0.2f

// scal layout (64 floats = 256 B, all zeroed); ALL writes to this region are
// ATOMIC — mixed atomic/plain stores on one line across non-coherent XCD L2s
// caused R11's flaky post-timing divergence.
//  [0]      ea_sum        (atomic, k_prep)
//  [32+l]   dot_l l=0..2  (atomic, k_prep — separate 128B line from [0])
//  [48]     alloc counter (atomic, k_alloc)
#define SCAL_N 64

typedef __attribute__((ext_vector_type(8))) short bf16x8;
typedef __attribute__((ext_vector_type(4))) float f32x4;

__device__ __forceinline__ float wave_reduce_sum(float v){
  #pragma unroll
  for (int off = 32; off > 0; off >>= 1) v += __shfl_xor(v, off, 64);
  return v;
}
__device__ __forceinline__ unsigned short bfhi(float f){
  return (unsigned short)(__float_as_uint(f) >> 16);   // truncation; lo term compensates
}
__device__ __forceinline__ float bftof(unsigned short h){
  return __uint_as_float(((unsigned int)h) << 16);
}
__device__ __forceinline__ unsigned short rne_bf16(float f){
  unsigned int u = __float_as_uint(f);
  u += 0x7FFF + ((u >> 16) & 1);
  return (unsigned short)(u >> 16);
}

// ---- fused prep: convW | convE | out_init | dots | ea_sum | deg -------------
#define PB_CONVW 640                    // 5*32768/256
#define PB_CONVE (PB_CONVW + 50)        // NV*H/256
#define PB_OUT   (PB_CONVE + 8)         // NG/256
#define PB_DOTS  (PB_OUT + 1)           // 3 waves in one block
#define PB_EASUM (PB_DOTS + 256)
#define PB_DEG   (PB_EASUM + 1954)      // (E+N)/256
__global__ __launch_bounds__(256) void k_prep(
    const float* __restrict__ gat_W, const float* __restrict__ lin_W,
    unsigned short* __restrict__ Wf,
    const float* __restrict__ emb, unsigned short* __restrict__ embb,
    const float* __restrict__ ea, const float* __restrict__ ew,
    const float* __restrict__ ae, float* __restrict__ scal,
    const float* __restrict__ wp_b, float* __restrict__ out,
    const int* __restrict__ ei, int* __restrict__ deg)
{
  int b = blockIdx.x, tid = threadIdx.x;
  if (b < PB_CONVW){
    // W -> bf16 hi/lo in MFMA B-fragment order:
    // idx = m*32768 + p*16384 + k0i*4096 + ct*512 + lane*8 + j
    // k = k0i*32 + (lane>>4)*8 + j, n = ct*16 + (lane&15)
    int i = b*256 + tid;
    int m   = i >> 15;
    int r   = i & 32767;
    int p   = r >> 14;
    int r2  = r & 16383;
    int k0i = r2 >> 12;
    int r3  = r2 & 4095;
    int ct  = r3 >> 9;
    int r4  = r3 & 511;
    int lane= r4 >> 3;
    int j   = r4 & 7;
    int q = lane >> 4, ln = lane & 15;
    int k = k0i*32 + q*8 + j;
    int n = ct*16 + ln;
    const float* src = (m < 3) ? (gat_W + m*16384) : (lin_W + (m-3)*16384);
    float w = src[k*H + n];
    unsigned short hi = bfhi(w);
    Wf[i] = (p == 0) ? hi : bfhi(w - bftof(hi));
  } else if (b < PB_CONVE){
    int i = (b - PB_CONVW)*256 + tid;
    if (i < NV*H) embb[i] = rne_bf16(emb[i]);
  } else if (b < PB_OUT){
    int g = (b - PB_CONVE)*256 + tid;
    if (g < NG) out[g] = wp_b[0];
  } else if (b < PB_DOTS){
    int l = tid >> 6, ln = tid & 63;
    if (l < NLAYERS){
      float p = ew[l*H + ln]*ae[l*H + ln] + ew[l*H + ln + 64]*ae[l*H + ln + 64];
      p = wave_reduce_sum(p);
      if (ln == 0) atomicAdd(&scal[32 + l], p);
    }
  } else if (b < PB_EASUM){
    int i = (b - PB_DOTS)*256 + tid;
    int stride = 256*256;
    float v = 0.f;
    for (; i < N_EDGES; i += stride) v += ea[i];
    v = wave_reduce_sum(v);
    if ((tid & 63) == 0) atomicAdd(&scal[0], v);
  } else {
    int i = (b - PB_EASUM)*256 + tid;
    if (i < N_EDGES + N_NODES){
      int d = (i < N_EDGES) ? ei[N_EDGES + i] : (i - N_EDGES);
      atomicAdd(&deg[d], 1);
    }
  }
}

// block scan + one atomic per block (CSR range order across nodes irrelevant)
__global__ __launch_bounds__(256) void k_alloc(
    const int* __restrict__ deg, int* __restrict__ row_ptr, int* __restrict__ counter){
  __shared__ int wsum[4];
  __shared__ int base;
  int n = blockIdx.x * 256 + threadIdx.x;
  int d = (n < N_NODES) ? deg[n] : 0;
  int lane = threadIdx.x & 63, wid = threadIdx.x >> 6;
  int v = d;
  #pragma unroll
  for (int off = 1; off < 64; off <<= 1){
    int u = __shfl_up(v, off, 64);
    if (lane >= off) v += u;
  }
  if (lane == 63) wsum[wid] = v;
  __syncthreads();
  if (threadIdx.x == 0){
    int t0 = wsum[0], t1 = wsum[1], t2 = wsum[2], t3 = wsum[3];
    base = atomicAdd(counter, t0 + t1 + t2 + t3);
    wsum[0] = 0; wsum[1] = t0; wsum[2] = t0 + t1; wsum[3] = t0 + t1 + t2;
  }
  __syncthreads();
  if (n < N_NODES) row_ptr[n] = base + wsum[wid] + (v - d);
}

__global__ void k_scatter(const int* __restrict__ ei, const float* __restrict__ ea,
                          const float* __restrict__ scal, const int* __restrict__ row_ptr,
                          int* __restrict__ cursor, int* __restrict__ csr_src,
                          float* __restrict__ csr_ea){
  int i = blockIdx.x * blockDim.x + threadIdx.x;
  if (i >= N_EDGES + N_NODES) return;
  int s, d; float v;
  if (i < N_EDGES){ s = ei[i]; d = ei[N_EDGES + i]; v = ea[i]; }
  else            { s = d = i - N_EDGES; v = scal[0] * (1.0f / N_EDGES); }  // ea_mean
  int pos = row_ptr[d] + atomicAdd(&cursor[d], 1);
  csr_src[pos] = s;
  csr_ea[pos]  = v;
}

// ---- MFMA GEMM: bf16 A (native), split-bf16 W (2-term), 64KB W in LDS -------
// Block = 256 thr = 4 waves; block tile 256 rows; wave tile 64 rows (4 m-tiles).
// mode 0: Cb=bf16(acc), a_s=acc·att1, a_d=acc·att2
// mode 1: Cb=bf16(relu(acc+bias))
// mode 2: relu(acc+bias)·att1 -> atomicAdd out[batch[row]]
__global__ __launch_bounds__(256, 2) void k_gemm(
    const unsigned short* __restrict__ Ab, const int* __restrict__ xmap,
    const unsigned short* __restrict__ Wf,      // fragment-ordered, 32768 ushorts
    unsigned short* __restrict__ Cb,
    const float* __restrict__ att1, const float* __restrict__ att2,
    float* __restrict__ a_s_out, float* __restrict__ a_d_out,
    const float* __restrict__ bias,
    const int* __restrict__ batch, float* __restrict__ out,
    int mode)
{
  __shared__ unsigned short lw[32768];   // 64 KB: hi plane then lo plane
  int tid  = threadIdx.x;
  int w    = tid >> 6;
  int lane = tid & 63;
  int q    = lane >> 4;
  int ln   = lane & 15;
  int waveRow = blockIdx.x*256 + w*64;

  // A fragments: native bf16, 16 B per (m, k0i)
  bf16x8 af[4][4];
  #pragma unroll
  for (int m = 0; m < 4; ++m){
    int r = waveRow + m*16 + ln;
    if (r >= N_NODES) r = N_NODES - 1;
    if (xmap) r = xmap[r];
    const unsigned short* Ar = Ab + (size_t)r*H;
    #pragma unroll
    for (int k0i = 0; k0i < 4; ++k0i)
      af[m][k0i] = *(const bf16x8*)(Ar + k0i*32 + q*8);
  }

  // stage full W (64 KB, coalesced 16B/thread x 16)
  #pragma unroll
  for (int i = 0; i < 16; ++i){
    int idx = (i*256 + tid) * 8;
    *(bf16x8*)(lw + idx) = *(const bf16x8*)(Wf + idx);
  }
  __syncthreads();

  f32x4 acc[4][8];
  #pragma unroll
  for (int m = 0; m < 4; ++m)
    #pragma unroll
    for (int ct = 0; ct < 8; ++ct) acc[m][ct] = (f32x4){0.f,0.f,0.f,0.f};

  #pragma unroll
  for (int k0i = 0; k0i < 4; ++k0i){
    #pragma unroll
    for (int ct = 0; ct < 8; ++ct){
      bf16x8 bhi = *(const bf16x8*)(lw + k0i*4096 + ct*512 + lane*8);
      bf16x8 blo = *(const bf16x8*)(lw + 16384 + k0i*4096 + ct*512 + lane*8);
      #pragma unroll
      for (int m = 0; m < 4; ++m){
        acc[m][ct] = __builtin_amdgcn_mfma_f32_16x16x32_bf16(af[m][k0i], blo, acc[m][ct], 0,0,0);
        acc[m][ct] = __builtin_amdgcn_mfma_f32_16x16x32_bf16(af[m][k0i], bhi, acc[m][ct], 0,0,0);
      }
    }
  }

  // C/D layout: col = ct*16 + ln, row = (m-tile base) + q*4 + r
  if (mode == 0){
    float as_l[8], ad_l[8];
    #pragma unroll
    for (int ct = 0; ct < 8; ++ct){ as_l[ct] = att1[ct*16+ln]; ad_l[ct] = att2[ct*16+ln]; }
    #pragma unroll
    for (int m = 0; m < 4; ++m){
      #pragma unroll
      for (int r = 0; r < 4; ++r){
        int grow = waveRow + m*16 + q*4 + r;
        bool ok = grow < N_NODES;
        float ps = 0.f, pd = 0.f;
        #pragma unroll
        for (int ct = 0; ct < 8; ++ct){
          float v = acc[m][ct][r];
          if (ok) Cb[(size_t)grow*H + ct*16 + ln] = rne_bf16(v);
          ps += v * as_l[ct]; pd += v * ad_l[ct];
        }
        #pragma unroll
        for (int mk = 8; mk > 0; mk >>= 1){
          ps += __shfl_xor(ps, mk, 64);
          pd += __shfl_xor(pd, mk, 64);
        }
        if (ok && ln == 0){ a_s_out[grow] = ps; a_d_out[grow] = pd; }
      }
    }
  } else if (mode == 1){
    float b_l[8];
    #pragma unroll
    for (int ct = 0; ct < 8; ++ct) b_l[ct] = bias[ct*16+ln];
    #pragma unroll
    for (int m = 0; m < 4; ++m){
      #pragma unroll
      for (int r = 0; r < 4; ++r){
        int grow = waveRow + m*16 + q*4 + r;
        if (grow >= N_NODES) continue;
        #pragma unroll
        for (int ct = 0; ct < 8; ++ct)
          Cb[(size_t)grow*H + ct*16 + ln] = rne_bf16(fmaxf(acc[m][ct][r] + b_l[ct], 0.f));
      }
    }
  } else {
    float b_l[8], wp_l[8];
    #pragma unroll
    for (int ct = 0; ct < 8; ++ct){ b_l[ct] = bias[ct*16+ln]; wp_l[ct] = att1[ct*16+ln]; }
    #pragma unroll
    for (int m = 0; m < 4; ++m){
      #pragma unroll
      for (int r = 0; r < 4; ++r){
        int grow = waveRow + m*16 + q*4 + r;
        bool ok = grow < N_NODES;
        float ps = 0.f;
        #pragma unroll
        for (int ct = 0; ct < 8; ++ct)
          ps += fmaxf(acc[m][ct][r] + b_l[ct], 0.f) * wp_l[ct];
        #pragma unroll
        for (int mk = 8; mk > 0; mk >>= 1) ps += __shfl_xor(ps, mk, 64);
        if (ok && ln == 0) atomicAdd(&out[batch[grow]], ps);
      }
    }
  }
}

// ---- aggregate with per-wave LDS-staged edge weights ------------------------
// One wave per node. Prologue: lanes 0..cnt-1 compute (src, w=exp(leaky(logit)))
// once per edge (coalesced csr loads) and stash in this wave's 512B LDS slice.
// Hot loop: 8 induction-addressed LDS reads (broadcast, free) -> 8 independent
// row gathers -> 16 FMAs. No shuffles, no global (src,w) round-trip, no barrier
// (same-wave LDS; compiler inserts lgkmcnt waits).
__global__ __launch_bounds__(256, 4) void k_aggregate(
    const unsigned int* __restrict__ xtb, const float* __restrict__ a_s,
    const float* __restrict__ a_d, const int* __restrict__ csr_src,
    const float* __restrict__ csr_ea, const int* __restrict__ row_ptr,
    const int* __restrict__ deg, const float* __restrict__ scal, int l,
    const float* __restrict__ bias, unsigned int* __restrict__ hb)
{
  __shared__ int   ls[4][64];
  __shared__ float lw2[4][64];
  int wid = threadIdx.x >> 6;
  int n = __builtin_amdgcn_readfirstlane(blockIdx.x*4 + wid);
  if (n >= N_NODES) return;
  int lane = threadIdx.x & 63;
  int beg = row_ptr[n];
  int d   = deg[n];              // >= 1 (self loop)
  float adn = a_d[n];
  float dl  = scal[32 + l];

  float2 acc = make_float2(0.f, 0.f);
  float ss = 0.f;
  for (int base = 0; base < d; base += 64){
    int cnt = min(64, d - base);
    if (lane < cnt){
      int e = beg + base + lane;
      int s = csr_src[e];                      // coalesced
      float lg = a_s[s] + adn + dl*csr_ea[e];  // unstabilized exp is exact math
      lg = (lg > 0.f) ? lg : SLOPE*lg;
      ls[wid][lane]  = s;
      lw2[wid][lane] = __expf(lg);
    }
    for (int j0 = 0; j0 < cnt; j0 += 8){
      int s8[8]; float w8[8];
      #pragma unroll
      for (int u = 0; u < 8; ++u){
        int jj = j0 + u;
        int c  = jj < cnt ? jj : 0;
        s8[u] = ls[wid][c];
        w8[u] = (jj < cnt) ? lw2[wid][c] : 0.f;
      }
      unsigned int xv[8];
      #pragma unroll
      for (int u = 0; u < 8; ++u)
        xv[u] = xtb[(size_t)s8[u]*(H/2) + lane];
      #pragma unroll
      for (int u = 0; u < 8; ++u){
        float x0 = __uint_as_float(xv[u] << 16);          // col lane*2
        float x1 = __uint_as_float(xv[u] & 0xFFFF0000u);  // col lane*2+1
        ss    += w8[u];
        acc.x += w8[u] * x0;
        acc.y += w8[u] * x1;
      }
    }
  }

  float2 bv = *(const float2*)(bias + lane*2);
  acc.x = acc.x/ss + bv.x;
  acc.y = acc.y/ss + bv.y;
  float sq = wave_reduce_sum(acc.x*acc.x + acc.y*acc.y);
  float nrm = fmaxf(sqrtf(sq), 1e-12f);
  unsigned int pk = ((unsigned int)rne_bf16(acc.y/nrm) << 16) | rne_bf16(acc.x/nrm);
  hb[(size_t)n*(H/2) + lane] = pk;
}

// ---- launch -----------------------------------------------------------------
extern "C" void kernel_launch(void* const* d_in, const int* in_sizes, int n_in,
                              void* d_out, int out_size, void* d_ws, size_t ws_size,
                              hipStream_t stream) {
  const int*   x          = (const int*)  d_in[0];
  const int*   edge_index = (const int*)  d_in[1];
  const float* edge_attr  = (const float*)d_in[2];
  const int*   batch      = (const int*)  d_in[3];
  const float* emb        = (const float*)d_in[4];
  const float* gat_W      = (const float*)d_in[5];
  const float* att_src    = (const float*)d_in[6];
  const float* att_dst    = (const float*)d_in[7];
  const float* edge_W     = (const float*)d_in[8];
  const float* att_edge   = (const float*)d_in[9];
  const float* gat_b      = (const float*)d_in[10];
  const float* lin_W      = (const float*)d_in[11];
  const float* lin_b      = (const float*)d_in[12];
  const float* wp_W       = (const float*)d_in[13];
  const float* wp_b       = (const float*)d_in[14];
  float* out = (float*)d_out;

  // workspace layout — 16B-aligned bf16 arrays first, then 4B arrays
  unsigned short* hb  = (unsigned short*)d_ws;          // N*H bf16
  unsigned short* xtb = hb + (size_t)N_NODES*H;         // N*H bf16
  unsigned short* Wt  = xtb + (size_t)N_NODES*H;        // 5*32768
  unsigned short* embb= Wt + 5*32768;                   // NV*H
  float* a_s    = (float*)(embb + NV*H);                // N
  float* a_d    = a_s + N_NODES;                        // N
  float* csr_ea = a_d + N_NODES;                        // E+N
  float* scal   = csr_ea + (N_EDGES + N_NODES);         // SCAL_N (zeroed)
  int*   deg    = (int*)(scal + SCAL_N);                // N (zeroed)
  int*   cursor = deg + N_NODES;                        // N (zeroed)
  int*   row_ptr= cursor + N_NODES;                     // N
  int*   csr_src= row_ptr + N_NODES;                    // E+N

  hipMemsetAsync(scal, 0, (size_t)(SCAL_N + 2*N_NODES) * sizeof(float), stream);

  k_prep<<<PB_DEG, 256, 0, stream>>>(
      gat_W, lin_W, Wt, emb, embb, edge_attr, edge_W, att_edge, scal,
      wp_b, out, edge_index, deg);
  k_alloc<<<(N_NODES + 255)/256, 256, 0, stream>>>(deg, row_ptr, (int*)&scal[48]);
  k_scatter<<<(N_EDGES + N_NODES + 255)/256, 256, 0, stream>>>(
      edge_index, edge_attr, scal, row_ptr, cursor, csr_src, csr_ea);

  const int gemm_grid = (N_NODES + 255) / 256;
  for (int l = 0; l < NLAYERS; ++l){
    k_gemm<<<gemm_grid, 256, 0, stream>>>(
        (l == 0) ? embb : hb, (l == 0) ? x : nullptr,
        Wt + (size_t)l*32768, xtb,
        att_src + l*H, att_dst + l*H, a_s, a_d,
        nullptr, nullptr, nullptr, 0);
    k_aggregate<<<N_NODES/4, 256, 0, stream>>>(
        (const unsigned int*)xtb, a_s, a_d, csr_src, csr_ea, row_ptr, deg,
        scal, l, gat_b + l*H, (unsigned int*)hb);
  }
  // dense 1: hb -> xtb (relu+bias, bf16)
  k_gemm<<<gemm_grid, 256, 0, stream>>>(
      hb, nullptr, Wt + (size_t)3*32768, xtb,
      nullptr, nullptr, nullptr, nullptr, lin_b, nullptr, nullptr, 1);
  // dense 2 + fused readout: relu(xtb@W+b)·wp -> atomicAdd out[batch]
  k_gemm<<<gemm_grid, 256, 0, stream>>>(
      xtb, nullptr, Wt + (size_t)4*32768, nullptr,
      wp_W, nullptr, nullptr, nullptr, lin_b + H, batch, out, 2);
}

// Round 14
// 337.746 us; speedup vs baseline: 1.1041x; 1.1041x over previous
//
#include <hip/hip_runtime.h>
#include <math.h>

#define N_NODES 100000
#define N_EDGES 400000
#define NG 2048
#define H 128
#define NV 100
#define NLAYERS 3
#define SLOPE 0.2f

// scal layout (64 floats = 256 B, all zeroed); ALL writes to this region are
// ATOMIC — mixed atomic/plain stores on one line across non-coherent XCD L2s
// caused R11's flaky post-timing divergence.
//  [0]      ea_sum        (atomic, k_prep)
//  [32+l]   dot_l l=0..2  (atomic, k_prep — separate 128B line from [0])
//  [48]     alloc counter (atomic, k_alloc)
#define SCAL_N 64

typedef __attribute__((ext_vector_type(8))) short bf16x8;
typedef __attribute__((ext_vector_type(4))) float f32x4;

__device__ __forceinline__ float wave_reduce_sum(float v){
  #pragma unroll
  for (int off = 32; off > 0; off >>= 1) v += __shfl_xor(v, off, 64);
  return v;
}
__device__ __forceinline__ unsigned short bfhi(float f){
  return (unsigned short)(__float_as_uint(f) >> 16);   // truncation; lo term compensates
}
__device__ __forceinline__ float bftof(unsigned short h){
  return __uint_as_float(((unsigned int)h) << 16);
}
__device__ __forceinline__ unsigned short rne_bf16(float f){
  unsigned int u = __float_as_uint(f);
  u += 0x7FFF + ((u >> 16) & 1);
  return (unsigned short)(u >> 16);
}

// ---- fused prep: convW | convE | out_init | dots | ea_sum | deg -------------
#define PB_CONVW 640                    // 5*32768/256
#define PB_CONVE (PB_CONVW + 50)        // NV*H/256
#define PB_OUT   (PB_CONVE + 8)         // NG/256
#define PB_DOTS  (PB_OUT + 1)           // 3 waves in one block
#define PB_EASUM (PB_DOTS + 256)
#define PB_DEG   (PB_EASUM + 1954)      // (E+N)/256
__global__ __launch_bounds__(256) void k_prep(
    const float* __restrict__ gat_W, const float* __restrict__ lin_W,
    unsigned short* __restrict__ Wf,
    const float* __restrict__ emb, unsigned short* __restrict__ embb,
    const float* __restrict__ ea, const float* __restrict__ ew,
    const float* __restrict__ ae, float* __restrict__ scal,
    const float* __restrict__ wp_b, float* __restrict__ out,
    const int* __restrict__ ei, int* __restrict__ deg)
{
  int b = blockIdx.x, tid = threadIdx.x;
  if (b < PB_CONVW){
    // W -> bf16 hi/lo in MFMA B-fragment order:
    // idx = m*32768 + p*16384 + k0i*4096 + ct*512 + lane*8 + j
    // k = k0i*32 + (lane>>4)*8 + j, n = ct*16 + (lane&15)
    int i = b*256 + tid;
    int m   = i >> 15;
    int r   = i & 32767;
    int p   = r >> 14;
    int r2  = r & 16383;
    int k0i = r2 >> 12;
    int r3  = r2 & 4095;
    int ct  = r3 >> 9;
    int r4  = r3 & 511;
    int lane= r4 >> 3;
    int j   = r4 & 7;
    int q = lane >> 4, ln = lane & 15;
    int k = k0i*32 + q*8 + j;
    int n = ct*16 + ln;
    const float* src = (m < 3) ? (gat_W + m*16384) : (lin_W + (m-3)*16384);
    float w = src[k*H + n];
    unsigned short hi = bfhi(w);
    Wf[i] = (p == 0) ? hi : bfhi(w - bftof(hi));
  } else if (b < PB_CONVE){
    int i = (b - PB_CONVW)*256 + tid;
    if (i < NV*H) embb[i] = rne_bf16(emb[i]);
  } else if (b < PB_OUT){
    int g = (b - PB_CONVE)*256 + tid;
    if (g < NG) out[g] = wp_b[0];
  } else if (b < PB_DOTS){
    int l = tid >> 6, ln = tid & 63;
    if (l < NLAYERS){
      float p = ew[l*H + ln]*ae[l*H + ln] + ew[l*H + ln + 64]*ae[l*H + ln + 64];
      p = wave_reduce_sum(p);
      if (ln == 0) atomicAdd(&scal[32 + l], p);
    }
  } else if (b < PB_EASUM){
    int i = (b - PB_DOTS)*256 + tid;
    int stride = 256*256;
    float v = 0.f;
    for (; i < N_EDGES; i += stride) v += ea[i];
    v = wave_reduce_sum(v);
    if ((tid & 63) == 0) atomicAdd(&scal[0], v);
  } else {
    int i = (b - PB_EASUM)*256 + tid;
    if (i < N_EDGES + N_NODES){
      int d = (i < N_EDGES) ? ei[N_EDGES + i] : (i - N_EDGES);
      atomicAdd(&deg[d], 1);
    }
  }
}

// block scan + one atomic per block (CSR range order across nodes irrelevant)
__global__ __launch_bounds__(256) void k_alloc(
    const int* __restrict__ deg, int* __restrict__ row_ptr, int* __restrict__ counter){
  __shared__ int wsum[4];
  __shared__ int base;
  int n = blockIdx.x * 256 + threadIdx.x;
  int d = (n < N_NODES) ? deg[n] : 0;
  int lane = threadIdx.x & 63, wid = threadIdx.x >> 6;
  int v = d;
  #pragma unroll
  for (int off = 1; off < 64; off <<= 1){
    int u = __shfl_up(v, off, 64);
    if (lane >= off) v += u;
  }
  if (lane == 63) wsum[wid] = v;
  __syncthreads();
  if (threadIdx.x == 0){
    int t0 = wsum[0], t1 = wsum[1], t2 = wsum[2], t3 = wsum[3];
    base = atomicAdd(counter, t0 + t1 + t2 + t3);
    wsum[0] = 0; wsum[1] = t0; wsum[2] = t0 + t1; wsum[3] = t0 + t1 + t2;
  }
  __syncthreads();
  if (n < N_NODES) row_ptr[n] = base + wsum[wid] + (v - d);
}

__global__ void k_scatter(const int* __restrict__ ei, const float* __restrict__ ea,
                          const float* __restrict__ scal, const int* __restrict__ row_ptr,
                          int* __restrict__ cursor, int* __restrict__ csr_src,
                          float* __restrict__ csr_ea){
  int i = blockIdx.x * blockDim.x + threadIdx.x;
  if (i >= N_EDGES + N_NODES) return;
  int s, d; float v;
  if (i < N_EDGES){ s = ei[i]; d = ei[N_EDGES + i]; v = ea[i]; }
  else            { s = d = i - N_EDGES; v = scal[0] * (1.0f / N_EDGES); }  // ea_mean
  int pos = row_ptr[d] + atomicAdd(&cursor[d], 1);
  csr_src[pos] = s;
  csr_ea[pos]  = v;
}

// ---- MFMA GEMM: bf16 A (native), split-bf16 W (2-term), 64KB W in LDS -------
// Block = 256 thr = 4 waves; block tile 256 rows; wave tile 64 rows (4 m-tiles).
// mode 0: Cb=bf16(acc), a_s=acc·att1, a_d=acc·att2
// mode 1: Cb=bf16(relu(acc+bias))
// mode 2: relu(acc+bias)·att1 -> atomicAdd out[batch[row]]
__global__ __launch_bounds__(256, 2) void k_gemm(
    const unsigned short* __restrict__ Ab, const int* __restrict__ xmap,
    const unsigned short* __restrict__ Wf,      // fragment-ordered, 32768 ushorts
    unsigned short* __restrict__ Cb,
    const float* __restrict__ att1, const float* __restrict__ att2,
    float* __restrict__ a_s_out, float* __restrict__ a_d_out,
    const float* __restrict__ bias,
    const int* __restrict__ batch, float* __restrict__ out,
    int mode)
{
  __shared__ unsigned short lw[32768];   // 64 KB: hi plane then lo plane
  int tid  = threadIdx.x;
  int w    = tid >> 6;
  int lane = tid & 63;
  int q    = lane >> 4;
  int ln   = lane & 15;
  int waveRow = blockIdx.x*256 + w*64;

  // A fragments: native bf16, 16 B per (m, k0i)
  bf16x8 af[4][4];
  #pragma unroll
  for (int m = 0; m < 4; ++m){
    int r = waveRow + m*16 + ln;
    if (r >= N_NODES) r = N_NODES - 1;
    if (xmap) r = xmap[r];
    const unsigned short* Ar = Ab + (size_t)r*H;
    #pragma unroll
    for (int k0i = 0; k0i < 4; ++k0i)
      af[m][k0i] = *(const bf16x8*)(Ar + k0i*32 + q*8);
  }

  // stage full W (64 KB, coalesced 16B/thread x 16)
  #pragma unroll
  for (int i = 0; i < 16; ++i){
    int idx = (i*256 + tid) * 8;
    *(bf16x8*)(lw + idx) = *(const bf16x8*)(Wf + idx);
  }
  __syncthreads();

  f32x4 acc[4][8];
  #pragma unroll
  for (int m = 0; m < 4; ++m)
    #pragma unroll
    for (int ct = 0; ct < 8; ++ct) acc[m][ct] = (f32x4){0.f,0.f,0.f,0.f};

  #pragma unroll
  for (int k0i = 0; k0i < 4; ++k0i){
    #pragma unroll
    for (int ct = 0; ct < 8; ++ct){
      bf16x8 bhi = *(const bf16x8*)(lw + k0i*4096 + ct*512 + lane*8);
      bf16x8 blo = *(const bf16x8*)(lw + 16384 + k0i*4096 + ct*512 + lane*8);
      #pragma unroll
      for (int m = 0; m < 4; ++m){
        acc[m][ct] = __builtin_amdgcn_mfma_f32_16x16x32_bf16(af[m][k0i], blo, acc[m][ct], 0,0,0);
        acc[m][ct] = __builtin_amdgcn_mfma_f32_16x16x32_bf16(af[m][k0i], bhi, acc[m][ct], 0,0,0);
      }
    }
  }

  // C/D layout: col = ct*16 + ln, row = (m-tile base) + q*4 + r
  if (mode == 0){
    float as_l[8], ad_l[8];
    #pragma unroll
    for (int ct = 0; ct < 8; ++ct){ as_l[ct] = att1[ct*16+ln]; ad_l[ct] = att2[ct*16+ln]; }
    #pragma unroll
    for (int m = 0; m < 4; ++m){
      #pragma unroll
      for (int r = 0; r < 4; ++r){
        int grow = waveRow + m*16 + q*4 + r;
        bool ok = grow < N_NODES;
        float ps = 0.f, pd = 0.f;
        #pragma unroll
        for (int ct = 0; ct < 8; ++ct){
          float v = acc[m][ct][r];
          if (ok) Cb[(size_t)grow*H + ct*16 + ln] = rne_bf16(v);
          ps += v * as_l[ct]; pd += v * ad_l[ct];
        }
        #pragma unroll
        for (int mk = 8; mk > 0; mk >>= 1){
          ps += __shfl_xor(ps, mk, 64);
          pd += __shfl_xor(pd, mk, 64);
        }
        if (ok && ln == 0){ a_s_out[grow] = ps; a_d_out[grow] = pd; }
      }
    }
  } else if (mode == 1){
    float b_l[8];
    #pragma unroll
    for (int ct = 0; ct < 8; ++ct) b_l[ct] = bias[ct*16+ln];
    #pragma unroll
    for (int m = 0; m < 4; ++m){
      #pragma unroll
      for (int r = 0; r < 4; ++r){
        int grow = waveRow + m*16 + q*4 + r;
        if (grow >= N_NODES) continue;
        #pragma unroll
        for (int ct = 0; ct < 8; ++ct)
          Cb[(size_t)grow*H + ct*16 + ln] = rne_bf16(fmaxf(acc[m][ct][r] + b_l[ct], 0.f));
      }
    }
  } else {
    float b_l[8], wp_l[8];
    #pragma unroll
    for (int ct = 0; ct < 8; ++ct){ b_l[ct] = bias[ct*16+ln]; wp_l[ct] = att1[ct*16+ln]; }
    #pragma unroll
    for (int m = 0; m < 4; ++m){
      #pragma unroll
      for (int r = 0; r < 4; ++r){
        int grow = waveRow + m*16 + q*4 + r;
        bool ok = grow < N_NODES;
        float ps = 0.f;
        #pragma unroll
        for (int ct = 0; ct < 8; ++ct)
          ps += fmaxf(acc[m][ct][r] + b_l[ct], 0.f) * wp_l[ct];
        #pragma unroll
        for (int mk = 8; mk > 0; mk >>= 1) ps += __shfl_xor(ps, mk, 64);
        if (ok && ln == 0) atomicAdd(&out[batch[grow]], ps);
      }
    }
  }
}

// ---- aggregate: TWO nodes per wave, 4 cols/lane (uint2 = 4 bf16) ------------
// Half h = lane>>5 owns node n = blk*8 + wid*2 + h; lane c = lane&31 covers
// cols 4c..4c+3. Prologue stages (src, w) int2 pairs into LDS with w=0 pads,
// so the hot loop is maskless: 8 ds_read_b64 + 8 independent dwordx2 gathers
// + FMAs covering 16 node-edges per group. Same-wave LDS -> no barrier.
__global__ __launch_bounds__(256, 4) void k_aggregate(
    const uint2* __restrict__ xtb2, const float* __restrict__ a_s,
    const float* __restrict__ a_d, const int* __restrict__ csr_src,
    const float* __restrict__ csr_ea, const int* __restrict__ row_ptr,
    const int* __restrict__ deg, const float* __restrict__ scal, int l,
    const float* __restrict__ bias, uint2* __restrict__ hb2)
{
  __shared__ int2 lsw[4][2][32];
  int wid  = threadIdx.x >> 6;
  int lane = threadIdx.x & 63;
  int h    = lane >> 5;
  int c    = lane & 31;
  int n    = blockIdx.x*8 + wid*2 + h;
  if (n >= N_NODES) return;
  int beg = row_ptr[n];
  int d   = deg[n];              // >= 1 (self loop)
  float adn = a_d[n];
  float dl  = scal[32 + l];
  int maxd = max(d, __shfl_xor(d, 32, 64));   // shared loop bound for both halves

  float4 acc = make_float4(0.f,0.f,0.f,0.f);
  float ss = 0.f;
  for (int base = 0; base < maxd; base += 32){
    // stage up to 32 edges for this half; pads get w=0 (contribute nothing)
    int s = 0; float wgt = 0.f;
    int j = base + c;
    if (j < d){
      int e = beg + j;
      s = csr_src[e];                          // coalesced per half
      float lg = a_s[s] + adn + dl*csr_ea[e];  // unstabilized exp is exact math
      lg = (lg > 0.f) ? lg : SLOPE*lg;
      wgt = __expf(lg);
    }
    int2 pk; pk.x = s; pk.y = __float_as_int(wgt);
    lsw[wid][h][c] = pk;

    int cnt8 = (min(32, maxd - base) + 7) & ~7;
    for (int j0 = 0; j0 < cnt8; j0 += 8){
      int2 sw[8];
      #pragma unroll
      for (int u = 0; u < 8; ++u) sw[u] = lsw[wid][h][j0 + u];
      uint2 xv[8];
      #pragma unroll
      for (int u = 0; u < 8; ++u)
        xv[u] = xtb2[(size_t)sw[u].x*(H/4) + c];
      #pragma unroll
      for (int u = 0; u < 8; ++u){
        float wgt8 = __int_as_float(sw[u].y);
        float x0 = __uint_as_float(xv[u].x << 16);
        float x1 = __uint_as_float(xv[u].x & 0xFFFF0000u);
        float x2 = __uint_as_float(xv[u].y << 16);
        float x3 = __uint_as_float(xv[u].y & 0xFFFF0000u);
        ss    += wgt8;
        acc.x += wgt8 * x0;
        acc.y += wgt8 * x1;
        acc.z += wgt8 * x2;
        acc.w += wgt8 * x3;
      }
    }
  }

  float4 bv = *(const float4*)(bias + c*4);
  float inv = 1.0f / ss;
  acc.x = acc.x*inv + bv.x;
  acc.y = acc.y*inv + bv.y;
  acc.z = acc.z*inv + bv.z;
  acc.w = acc.w*inv + bv.w;
  float sq = acc.x*acc.x + acc.y*acc.y + acc.z*acc.z + acc.w*acc.w;
  #pragma unroll
  for (int off = 16; off > 0; off >>= 1) sq += __shfl_xor(sq, off, 64);  // within half
  float rn = 1.0f / fmaxf(sqrtf(sq), 1e-12f);
  uint2 o;
  o.x = ((unsigned int)rne_bf16(acc.y*rn) << 16) | rne_bf16(acc.x*rn);
  o.y = ((unsigned int)rne_bf16(acc.w*rn) << 16) | rne_bf16(acc.z*rn);
  hb2[(size_t)n*(H/4) + c] = o;
}

// ---- launch -----------------------------------------------------------------
extern "C" void kernel_launch(void* const* d_in, const int* in_sizes, int n_in,
                              void* d_out, int out_size, void* d_ws, size_t ws_size,
                              hipStream_t stream) {
  const int*   x          = (const int*)  d_in[0];
  const int*   edge_index = (const int*)  d_in[1];
  const float* edge_attr  = (const float*)d_in[2];
  const int*   batch      = (const int*)  d_in[3];
  const float* emb        = (const float*)d_in[4];
  const float* gat_W      = (const float*)d_in[5];
  const float* att_src    = (const float*)d_in[6];
  const float* att_dst    = (const float*)d_in[7];
  const float* edge_W     = (const float*)d_in[8];
  const float* att_edge   = (const float*)d_in[9];
  const float* gat_b      = (const float*)d_in[10];
  const float* lin_W      = (const float*)d_in[11];
  const float* lin_b      = (const float*)d_in[12];
  const float* wp_W       = (const float*)d_in[13];
  const float* wp_b       = (const float*)d_in[14];
  float* out = (float*)d_out;

  // workspace layout — 16B-aligned bf16 arrays first, then 4B arrays
  unsigned short* hb  = (unsigned short*)d_ws;          // N*H bf16
  unsigned short* xtb = hb + (size_t)N_NODES*H;         // N*H bf16
  unsigned short* Wt  = xtb + (size_t)N_NODES*H;        // 5*32768
  unsigned short* embb= Wt + 5*32768;                   // NV*H
  float* a_s    = (float*)(embb + NV*H);                // N
  float* a_d    = a_s + N_NODES;                        // N
  float* csr_ea = a_d + N_NODES;                        // E+N
  float* scal   = csr_ea + (N_EDGES + N_NODES);         // SCAL_N (zeroed)
  int*   deg    = (int*)(scal + SCAL_N);                // N (zeroed)
  int*   cursor = deg + N_NODES;                        // N (zeroed)
  int*   row_ptr= cursor + N_NODES;                     // N
  int*   csr_src= row_ptr + N_NODES;                    // E+N

  hipMemsetAsync(scal, 0, (size_t)(SCAL_N + 2*N_NODES) * sizeof(float), stream);

  k_prep<<<PB_DEG, 256, 0, stream>>>(
      gat_W, lin_W, Wt, emb, embb, edge_attr, edge_W, att_edge, scal,
      wp_b, out, edge_index, deg);
  k_alloc<<<(N_NODES + 255)/256, 256, 0, stream>>>(deg, row_ptr, (int*)&scal[48]);
  k_scatter<<<(N_EDGES + N_NODES + 255)/256, 256, 0, stream>>>(
      edge_index, edge_attr, scal, row_ptr, cursor, csr_src, csr_ea);

  const int gemm_grid = (N_NODES + 255) / 256;
  for (int l = 0; l < NLAYERS; ++l){
    k_gemm<<<gemm_grid, 256, 0, stream>>>(
        (l == 0) ? embb : hb, (l == 0) ? x : nullptr,
        Wt + (size_t)l*32768, xtb,
        att_src + l*H, att_dst + l*H, a_s, a_d,
        nullptr, nullptr, nullptr, 0);
    k_aggregate<<<(N_NODES + 7)/8, 256, 0, stream>>>(
        (const uint2*)xtb, a_s, a_d, csr_src, csr_ea, row_ptr, deg,
        scal, l, gat_b + l*H, (uint2*)hb);
  }
  // dense 1: hb -> xtb (relu+bias, bf16)
  k_gemm<<<gemm_grid, 256, 0, stream>>>(
      hb, nullptr, Wt + (size_t)3*32768, xtb,
      nullptr, nullptr, nullptr, nullptr, lin_b, nullptr, nullptr, 1);
  // dense 2 + fused readout: relu(xtb@W+b)·wp -> atomicAdd out[batch]
  k_gemm<<<gemm_grid, 256, 0, stream>>>(
      xtb, nullptr, Wt + (size_t)4*32768, nullptr,
      wp_W, nullptr, nullptr, nullptr, lin_b + H, batch, out, 2);
}